// Round 7
// baseline (2510.147 us; speedup 1.0000x reference)
//
#include <hip/hip_runtime.h>

#define NT 25
#define NXY 448
#define NPIX (448*448)
#define PXY 115
#define SXY 111

#define TW 32
#define TH 8

// ---------------- K1: fused complex conv1(1->12,5x5)+ReLU -> conv2(12->12,3 temporal,
// register-resident scatter)+ReLU -> conv3(12->1) real part ; out = (x_re - denR*tsc)*pwv
// OUT: float32, real part only, C-order [25,448,448]
__global__ __launch_bounds__(256) void k_conv(
    const float* __restrict__ re, const float* __restrict__ im,
    const float* __restrict__ w1r, const float* __restrict__ w1i,
    const float* __restrict__ b1r, const float* __restrict__ b1i,
    const float* __restrict__ w2r, const float* __restrict__ w2i,
    const float* __restrict__ b2r, const float* __restrict__ b2i,
    const float* __restrict__ w3r, const float* __restrict__ w3i,
    const float* __restrict__ b3r,
    const float* __restrict__ tau_w, const float* __restrict__ p_w,
    const int* __restrict__ num_iter,
    float* __restrict__ out)
{
    // transposed weight layouts: output channel contiguous -> ds_read_b128
    __shared__ float s_w1[25*24];        // [tap][c r:0..11, i:12..23]
    __shared__ float s_w2[36*24];        // [(c1*3+dt)][c2 r:0..11, i:12..23]
    __shared__ float s_wb[76];           // b1r b1i b2r b2i w3r w3i (12 each) + b3r
    __shared__ float2 s_in[2][12][36];   // double-buffered input tile (re,im), 2-halo

    const int tid = threadIdx.x;
    const int tx = tid & 31;
    const int ty = tid >> 5;
    const int Y0 = blockIdx.x * TW;
    const int X0 = blockIdx.y * TH;

    for (int i = tid; i < 300; i += 256) {
        int c = i / 25, tap = i - c*25;             // global idx = c*25 + tap
        s_w1[tap*24 + c]      = w1r[i];
        s_w1[tap*24 + 12 + c] = w1i[i];
    }
    for (int i = tid; i < 432; i += 256) {
        int dt = i % 3; int t = i / 3; int c1 = t % 12; int c2 = t / 12; // i=(c2*12+c1)*3+dt
        s_w2[(c1*3+dt)*24 + c2]      = w2r[i];
        s_w2[(c1*3+dt)*24 + 12 + c2] = w2i[i];
    }
    if (tid < 12) {
        s_wb[tid]    = b1r[tid];  s_wb[12+tid] = b1i[tid];
        s_wb[24+tid] = b2r[tid];  s_wb[36+tid] = b2i[tid];
        s_wb[48+tid] = w3r[tid];  s_wb[60+tid] = w3i[tid];
    }
    if (tid == 0) s_wb[72] = b3r[0];

    const float tsc = fmaxf(tau_w[0], 0.f) / (float)num_iter[0];
    const float pwv = fmaxf(p_w[0], 0.f);

    // rotating conv2 accumulators: zN = tc=tf+1, zM = tc=tf, zO = tc=tf-1
    float zNr[12], zNi[12], zMr[12], zMi[12], zOr[12], zOi[12];

    #pragma unroll 1
    for (int tf = 0; tf <= NT; ++tf) {
        if (tf < NT) {
            const float* rp = re + (size_t)tf * NPIX;
            const float* ip = im + (size_t)tf * NPIX;
            float2* dst = &s_in[tf & 1][0][0];
            for (int idx = tid; idx < 12*36; idx += 256) {
                int r = idx / 36, c = idx - r*36;
                int gx = X0 + r - 2, gy = Y0 + c - 2;
                bool ok = (gx >= 0) && (gx < NXY) && (gy >= 0) && (gy < NXY);
                int cgx = ok ? gx : 0, cgy = ok ? gy : 0;
                size_t a = (size_t)cgx * NXY + cgy;
                float vr = rp[a], vi = ip[a];
                dst[idx] = make_float2(ok ? vr : 0.f, ok ? vi : 0.f);
            }
        }
        __syncthreads();
        if (tf == 0) {
            // init after barrier (biases now staged): zM = tc0 bias, zN = tc1 bias
            #pragma unroll
            for (int c = 0; c < 12; ++c) {
                zMr[c] = s_wb[24+c]; zMi[c] = s_wb[36+c];
                zNr[c] = s_wb[24+c]; zNi[c] = s_wb[36+c];
                zOr[c] = 0.f;        zOi[c] = 0.f;
            }
        }
        if (tf < NT) {
            // ---- conv1 (register h), SAME 5x5, zero-padded borders
            float hr[12], hi[12];
            #pragma unroll
            for (int c = 0; c < 12; ++c) { hr[c] = s_wb[c]; hi[c] = s_wb[12+c]; }
            const float2 (*sin_)[36] = s_in[tf & 1];
            #pragma unroll 1
            for (int ky = 0; ky < 5; ++ky) {
                const float* wrow = &s_w1[ky*5*24];
                const float2* irow = &sin_[ty+ky][tx];
                #pragma unroll
                for (int kx = 0; kx < 5; ++kx) {
                    float2 v = irow[kx];
                    const float* wp = wrow + kx*24;
                    #pragma unroll
                    for (int c = 0; c < 12; ++c) {
                        hr[c] += v.x*wp[c]    - v.y*wp[12+c];
                        hi[c] += v.x*wp[12+c] + v.y*wp[c];
                    }
                }
            }
            #pragma unroll
            for (int c = 0; c < 12; ++c) { hr[c] = fmaxf(hr[c],0.f); hi[c] = fmaxf(hi[c],0.f); }
            // ---- conv2 scatter: dt=0 -> zN, dt=1 -> zM, dt=2 -> zO
            #pragma unroll
            for (int c1 = 0; c1 < 12; ++c1) {
                float xr = hr[c1], xi = hi[c1];
                {   const float* wp = &s_w2[(c1*3+0)*24];
                    #pragma unroll
                    for (int c2 = 0; c2 < 12; ++c2) {
                        zNr[c2] += xr*wp[c2]    - xi*wp[12+c2];
                        zNi[c2] += xr*wp[12+c2] + xi*wp[c2];
                    } }
                {   const float* wp = &s_w2[(c1*3+1)*24];
                    #pragma unroll
                    for (int c2 = 0; c2 < 12; ++c2) {
                        zMr[c2] += xr*wp[c2]    - xi*wp[12+c2];
                        zMi[c2] += xr*wp[12+c2] + xi*wp[c2];
                    } }
                {   const float* wp = &s_w2[(c1*3+2)*24];
                    #pragma unroll
                    for (int c2 = 0; c2 < 12; ++c2) {
                        zOr[c2] += xr*wp[c2]    - xi*wp[12+c2];
                        zOi[c2] += xr*wp[12+c2] + xi*wp[c2];
                    } }
            }
        }
        if (tf >= 1) {
            // finalize tc = tf-1: relu(zO) -> conv3 real part -> epilogue
            float dR = s_wb[72];
            #pragma unroll
            for (int c = 0; c < 12; ++c)
                dR += fmaxf(zOr[c],0.f)*s_wb[48+c] - fmaxf(zOi[c],0.f)*s_wb[60+c];
            size_t idx = (size_t)(tf-1)*NPIX + (size_t)(X0+ty)*NXY + (Y0+tx);
            out[idx] = (re[idx] - dR * tsc) * pwv;
        }
        if (tf < NT) {
            // rotate: zO<-zM, zM<-zN, zN<-bias2
            #pragma unroll
            for (int c = 0; c < 12; ++c) {
                zOr[c] = zMr[c];     zOi[c] = zMi[c];
                zMr[c] = zNr[c];     zMi[c] = zNi[c];
                zNr[c] = s_wb[24+c]; zNi[c] = s_wb[36+c];
            }
        }
    }
}

// ---------------- K2: Gram matrices G_b = M_b M_b^H  (80 x 5x5 complex Hermitian)
__global__ __launch_bounds__(256) void k_gram(
    const float* __restrict__ re, const float* __restrict__ im,
    float* __restrict__ gG)
{
    const int b = blockIdx.x;            // 0..79  = chunk*16 + i*4 + j
    const int chunk = b >> 4;
    const int pidx = b & 15;
    const int X0 = (pidx >> 2) * SXY;
    const int Y0 = (pidx & 3) * SXY;
    const int tid = threadIdx.x;

    float acc[50];
    #pragma unroll
    for (int k = 0; k < 50; ++k) acc[k] = 0.f;

    const int npx = PXY * PXY;           // 13225
    for (int pi = tid; pi < npx; pi += 256) {
        int px = pi / PXY, py = pi % PXY;
        size_t base = (size_t)(X0 + px) * NXY + (Y0 + py);
        float xr[5], xi[5];
        #pragma unroll
        for (int r = 0; r < 5; ++r) {
            size_t a = (size_t)(chunk*5 + r) * NPIX + base;
            xr[r] = re[a]; xi[r] = im[a];
        }
        #pragma unroll
        for (int t1 = 0; t1 < 5; ++t1)
            #pragma unroll
            for (int t2 = 0; t2 < 5; ++t2) {
                acc[(t1*5+t2)*2]   += xr[t1]*xr[t2] + xi[t1]*xi[t2];
                acc[(t1*5+t2)*2+1] += xi[t1]*xr[t2] - xr[t1]*xi[t2];
            }
    }
    #pragma unroll
    for (int k = 0; k < 50; ++k) {
        float v = acc[k];
        for (int m = 32; m > 0; m >>= 1) v += __shfl_xor(v, m, 64);
        acc[k] = v;
    }
    __shared__ float s_red[4][50];
    int lane = tid & 63, wid = tid >> 6;
    if (lane == 0) {
        #pragma unroll
        for (int k = 0; k < 50; ++k) s_red[wid][k] = acc[k];
    }
    __syncthreads();
    if (tid < 50) {
        gG[b*50 + tid] = s_red[0][tid] + s_red[1][tid] + s_red[2][tid] + s_red[3][tid];
    }
}

// ---------------- K3: 5x5 complex Hermitian Jacobi eigensolve -> W = V f(Lambda) V^H
__global__ void k_eig(const float* __restrict__ gG, const float* __restrict__ thres,
                      float* __restrict__ gW)
{
    int b = blockIdx.x * 64 + threadIdx.x;
    if (b >= 80) return;
    float Ar[5][5], Ai[5][5], Vr[5][5], Vi[5][5];
    #pragma unroll
    for (int a = 0; a < 5; ++a)
        #pragma unroll
        for (int c = 0; c < 5; ++c) {
            Ar[a][c] = gG[b*50 + (a*5+c)*2];
            Ai[a][c] = gG[b*50 + (a*5+c)*2 + 1];
            Vr[a][c] = (a==c) ? 1.f : 0.f;
            Vi[a][c] = 0.f;
        }
    for (int sw = 0; sw < 9; ++sw) {
        #pragma unroll
        for (int p = 0; p < 4; ++p) {
            #pragma unroll
            for (int q = p+1; q < 5; ++q) {
                float apr = Ar[p][q], api = Ai[p][q];
                float n2 = apr*apr + api*api;
                if (n2 > 1e-24f) {
                    float mlen = sqrtf(n2);
                    float phr = apr / mlen, phi = api / mlen;
                    float tau = (Ar[q][q] - Ar[p][p]) / (2.f * mlen);
                    float tt = (tau >= 0.f ? 1.f : -1.f) / (fabsf(tau) + sqrtf(1.f + tau*tau));
                    float cc = 1.f / sqrtf(1.f + tt*tt);
                    float ss = tt * cc;
                    float wr2 = ss * phr, wi2 = ss * phi;   // w = s*e^{i phi}
                    #pragma unroll
                    for (int k = 0; k < 5; ++k) {
                        float xr = Ar[k][p], xi2 = Ai[k][p];
                        float yr = Ar[k][q], yi = Ai[k][q];
                        Ar[k][p] = cc*xr - (wr2*yr + wi2*yi);
                        Ai[k][p] = cc*xi2 - (wr2*yi - wi2*yr);
                        Ar[k][q] = wr2*xr - wi2*xi2 + cc*yr;
                        Ai[k][q] = wr2*xi2 + wi2*xr + cc*yi;
                        float vxr = Vr[k][p], vxi = Vi[k][p];
                        float vyr = Vr[k][q], vyi = Vi[k][q];
                        Vr[k][p] = cc*vxr - (wr2*vyr + wi2*vyi);
                        Vi[k][p] = cc*vxi - (wr2*vyi - wi2*vyr);
                        Vr[k][q] = wr2*vxr - wi2*vxi + cc*vyr;
                        Vi[k][q] = wr2*vxi + wi2*vxr + cc*vyi;
                    }
                    #pragma unroll
                    for (int k = 0; k < 5; ++k) {
                        float xr = Ar[p][k], xi2 = Ai[p][k];
                        float yr = Ar[q][k], yi = Ai[q][k];
                        Ar[p][k] = cc*xr - (wr2*yr - wi2*yi);
                        Ai[p][k] = cc*xi2 - (wr2*yi + wi2*yr);
                        Ar[q][k] = wr2*xr + wi2*xi2 + cc*yr;
                        Ai[q][k] = wr2*xi2 - wi2*xr + cc*yi;
                    }
                }
            }
        }
    }
    float sv[5], s0 = 0.f;
    #pragma unroll
    for (int k = 0; k < 5; ++k) { sv[k] = sqrtf(fmaxf(Ar[k][k], 0.f)); s0 = fmaxf(s0, sv[k]); }
    float th = fmaxf(thres[b], 0.f) * s0;
    float ratio[5];
    #pragma unroll
    for (int k = 0; k < 5; ++k)
        ratio[k] = sv[k] > 0.f ? fmaxf(sv[k] - th, 0.f) / sv[k] : 0.f;
    #pragma unroll
    for (int a = 0; a < 5; ++a)
        #pragma unroll
        for (int c = 0; c < 5; ++c) {
            float wr = 0.f, wi = 0.f;
            #pragma unroll
            for (int k = 0; k < 5; ++k) {
                wr += ratio[k] * (Vr[a][k]*Vr[c][k] + Vi[a][k]*Vi[c][k]);
                wi += ratio[k] * (Vi[a][k]*Vr[c][k] - Vr[a][k]*Vi[c][k]);
            }
            gW[b*50 + (a*5+c)*2]   = wr;
            gW[b*50 + (a*5+c)*2+1] = wi;
        }
}

// ---------------- K3b: region-averaged W (7x7 overlap regions per chunk), includes 1/cnt
__global__ void k_wavg(const float* __restrict__ gW, float* __restrict__ gA)
{
    int blk = blockIdx.x;         // chunk*49 + rx*7 + ry
    int e = threadIdx.x;
    if (e >= 25) return;
    int chunk = blk / 49;
    int rem = blk % 49;
    int rx = rem / 7, ry = rem % 7;
    int i0 = rx >> 1, i1 = (rx + 1) >> 1;
    int j0 = ry >> 1, j1 = (ry + 1) >> 1;
    float sr = 0.f, si = 0.f; int cnt = 0;
    for (int i = i0; i <= i1; ++i)
        for (int j = j0; j <= j1; ++j) {
            int b = chunk*16 + i*4 + j;
            sr += gW[b*50 + e*2];
            si += gW[b*50 + e*2 + 1];
            ++cnt;
        }
    float inv = 1.f / (float)cnt;
    gA[blk*50 + e*2]   = sr * inv;
    gA[blk*50 + e*2+1] = si * inv;
}

// ---------------- K4: q_re = Re(Wavg * x5) ; out += q_re*(1-p_w)   (fp32 RMW)
__global__ __launch_bounds__(256) void k_final(
    const float* __restrict__ re, const float* __restrict__ im,
    const float* __restrict__ gA, const float* __restrict__ p_w,
    float* __restrict__ out)
{
    int pix = blockIdx.x * 256 + threadIdx.x;
    int chunk = blockIdx.y;
    int X = pix / NXY, Y = pix % NXY;
    int i_lo = (X - 4) / SXY; if (i_lo < 0) i_lo = 0;
    int i_hi = X / SXY;       if (i_hi > 3) i_hi = 3;
    int j_lo = (Y - 4) / SXY; if (j_lo < 0) j_lo = 0;
    int j_hi = Y / SXY;       if (j_hi > 3) j_hi = 3;
    int rx = i_lo + i_hi, ry = j_lo + j_hi;
    const float* wa = gA + (size_t)(chunk*49 + rx*7 + ry) * 50;
    float Wr[5][5], Wi[5][5];
    #pragma unroll
    for (int a = 0; a < 5; ++a)
        #pragma unroll
        for (int r = 0; r < 5; ++r) {
            Wr[a][r] = wa[(a*5+r)*2];
            Wi[a][r] = wa[(a*5+r)*2+1];
        }
    float xr[5], xi[5];
    #pragma unroll
    for (int r = 0; r < 5; ++r) {
        size_t a = (size_t)(chunk*5+r)*NPIX + pix;
        xr[r] = re[a]; xi[r] = im[a];
    }
    float qwv = 1.f - p_w[0];
    #pragma unroll
    for (int tl = 0; tl < 5; ++tl) {
        float qr = 0.f;
        #pragma unroll
        for (int r = 0; r < 5; ++r)
            qr += Wr[tl][r]*xr[r] - Wi[tl][r]*xi[r];
        size_t idx = (size_t)(chunk*5+tl)*NPIX + pix;
        out[idx] += qr*qwv;
    }
}

extern "C" void kernel_launch(void* const* d_in, const int* in_sizes, int n_in,
                              void* d_out, int out_size, void* d_ws, size_t ws_size,
                              hipStream_t stream)
{
    const float* re    = (const float*)d_in[0];
    const float* im    = (const float*)d_in[1];
    const float* w1r   = (const float*)d_in[2];
    const float* w1i   = (const float*)d_in[3];
    const float* b1r   = (const float*)d_in[4];
    const float* b1i   = (const float*)d_in[5];
    const float* w2r   = (const float*)d_in[6];
    const float* w2i   = (const float*)d_in[7];
    const float* b2r   = (const float*)d_in[8];
    const float* b2i   = (const float*)d_in[9];
    const float* w3r   = (const float*)d_in[10];
    const float* w3i   = (const float*)d_in[11];
    const float* b3r   = (const float*)d_in[12];
    const float* thres = (const float*)d_in[14];
    const float* tau_w = (const float*)d_in[15];
    const float* p_w   = (const float*)d_in[16];
    const int* num_iter= (const int*)d_in[17];

    float* ws = (float*)d_ws;
    float* gG = ws;                 // 80*50 floats
    float* gW = gG + 80*50;         // 80*50 floats
    float* gA = gW + 80*50;         // 245*50 floats  (total ~81 KB)

    float* outf = (float*)d_out;

    dim3 g1(NXY/TW, NXY/TH);
    k_conv<<<g1, 256, 0, stream>>>(re, im, w1r, w1i, b1r, b1i, w2r, w2i,
                                   b2r, b2i, w3r, w3i, b3r,
                                   tau_w, p_w, num_iter, outf);
    k_gram<<<80, 256, 0, stream>>>(re, im, gG);
    k_eig<<<2, 64, 0, stream>>>(gG, thres, gW);
    k_wavg<<<245, 32, 0, stream>>>(gW, gA);
    dim3 g4(NPIX/256, 5);
    k_final<<<g4, 256, 0, stream>>>(re, im, gA, p_w, outf);
}

// Round 8
// 1425.504 us; speedup vs baseline: 1.7609x; 1.7609x over previous
//
#include <hip/hip_runtime.h>
#include <hip/hip_fp16.h>

#define NT 25
#define NXY 448
#define NPIX (448*448)
#define PXY 115
#define SXY 111

#define TW 32
#define TH 8

// ---------------- K1: fused complex conv1(1->12,5x5)+ReLU -> conv2(12->12,3 temporal)+ReLU
// -> conv3(12->1) real part ; out = (x_re - denR*tsc)*pwv   (fp32, [25,448,448])
// h1 kept per-pixel in LDS fp16 (own-thread access only -> no barrier); 1 barrier/frame.
__global__ __launch_bounds__(256) void k_conv(
    const float* __restrict__ re, const float* __restrict__ im,
    const float* __restrict__ w1r, const float* __restrict__ w1i,
    const float* __restrict__ b1r, const float* __restrict__ b1i,
    const float* __restrict__ w2r, const float* __restrict__ w2i,
    const float* __restrict__ b2r, const float* __restrict__ b2i,
    const float* __restrict__ w3r, const float* __restrict__ w3i,
    const float* __restrict__ b3r,
    const float* __restrict__ tau_w, const float* __restrict__ p_w,
    const int* __restrict__ num_iter,
    float* __restrict__ out)
{
    // transposed weights: output channel contiguous -> ds_read_b128 broadcasts
    __shared__ float s_w1[25*24];          // [tap*24 + (c | 12+c)]  (r | i)
    __shared__ float s_w2[36*24];          // [(c1*3+dt)*24 + (c2 | 12+c2)]
    __shared__ float s_wb[76];             // b1r b1i b2r b2i w3r w3i (12 each) + b3r
    __shared__ float2 s_in[2][12*36];      // double-buffered input tile, 2-halo
    __shared__ __half2 s_h1[3][12][TH*TW]; // per-pixel h1, 3 time slots

    const int tid = threadIdx.x;
    const int tx = tid & 31;
    const int ty = tid >> 5;
    const int Y0 = blockIdx.x * TW;
    const int X0 = blockIdx.y * TH;

    for (int i = tid; i < 300; i += 256) {
        int c = i / 25, tap = i - c*25;            // global idx = c*25 + tap
        s_w1[tap*24 + c]      = w1r[i];
        s_w1[tap*24 + 12 + c] = w1i[i];
    }
    for (int i = tid; i < 432; i += 256) {
        int dt = i % 3; int t = i / 3; int c1 = t % 12; int c2 = t / 12; // i=(c2*12+c1)*3+dt
        s_w2[(c1*3+dt)*24 + c2]      = w2r[i];
        s_w2[(c1*3+dt)*24 + 12 + c2] = w2i[i];
    }
    if (tid < 12) {
        s_wb[tid]    = b1r[tid];  s_wb[12+tid] = b1i[tid];
        s_wb[24+tid] = b2r[tid];  s_wb[36+tid] = b2i[tid];
        s_wb[48+tid] = w3r[tid];  s_wb[60+tid] = w3i[tid];
    }
    if (tid == 0) s_wb[72] = b3r[0];

    const float tsc = fmaxf(tau_w[0], 0.f) / (float)num_iter[0];
    const float pwv = fmaxf(p_w[0], 0.f);

    // tile-local halo coords for the two staging elements this thread owns
    const int r0 = tid / 36,        c0 = tid - r0*36;
    const int i1_ = tid + 256;
    const int r1 = i1_ / 36,        c1_ = i1_ - r1*36;
    const bool has1 = (i1_ < 432);

    auto ld_elem = [&](const float* rp, const float* ip, int r, int c) -> float2 {
        int gx = X0 + r - 2, gy = Y0 + c - 2;
        bool ok = (gx >= 0) && (gx < NXY) && (gy >= 0) && (gy < NXY);
        int cgx = ok ? gx : 0, cgy = ok ? gy : 0;
        size_t a = (size_t)cgx * NXY + cgy;
        float vr = rp[a], vi = ip[a];
        return make_float2(ok ? vr : 0.f, ok ? vi : 0.f);
    };

    // conv2+conv3+epilogue for output frame tc (reads own-pixel h1 slots, all valid)
    auto do_out = [&](int tc) {
        float zr[12], zi[12];
        #pragma unroll
        for (int c = 0; c < 12; ++c) { zr[c] = s_wb[24+c]; zi[c] = s_wb[36+c]; }
        #pragma unroll
        for (int dt = 0; dt < 3; ++dt) {
            int tt = tc - 1 + dt;
            if (tt >= 0 && tt < NT) {          // wave-uniform branch
                int sl = tt % 3;
                #pragma unroll
                for (int c1 = 0; c1 < 12; ++c1) {
                    __half2 h = s_h1[sl][c1][tid];
                    float xr = __low2float(h), xi = __high2float(h);
                    const float* wp = &s_w2[(c1*3+dt)*24];
                    #pragma unroll
                    for (int c2 = 0; c2 < 12; ++c2) {
                        zr[c2] += xr*wp[c2]    - xi*wp[12+c2];
                        zi[c2] += xr*wp[12+c2] + xi*wp[c2];
                    }
                }
            }
        }
        float dR = s_wb[72];
        #pragma unroll
        for (int c = 0; c < 12; ++c)
            dR += fmaxf(zr[c],0.f)*s_wb[48+c] - fmaxf(zi[c],0.f)*s_wb[60+c];
        size_t idx = (size_t)tc*NPIX + (size_t)(X0+ty)*NXY + (Y0+tx);
        out[idx] = (re[idx] - dR * tsc) * pwv;
    };

    // stage frame 0
    {
        const float* rp = re; const float* ip = im;
        s_in[0][tid] = ld_elem(rp, ip, r0, c0);
        if (has1) s_in[0][i1_] = ld_elem(rp, ip, r1, c1_);
    }
    __syncthreads();

    #pragma unroll 1
    for (int tf = 0; tf < NT; ++tf) {
        // prefetch frame tf+1 into registers (overlaps with compute below)
        float2 p0, p1;
        const bool pf = (tf + 1 < NT);
        if (pf) {
            const float* rp = re + (size_t)(tf+1) * NPIX;
            const float* ip = im + (size_t)(tf+1) * NPIX;
            p0 = ld_elem(rp, ip, r0, c0);
            if (has1) p1 = ld_elem(rp, ip, r1, c1_);
        }

        // ---- conv1 from s_in[tf&1]: 24 accumulators, b128 weight broadcasts
        float ar[12], ai[12];
        #pragma unroll
        for (int c = 0; c < 12; ++c) { ar[c] = s_wb[c]; ai[c] = s_wb[12+c]; }
        const float2* sin_ = s_in[tf & 1];
        #pragma unroll
        for (int ky = 0; ky < 5; ++ky) {
            const float2* irow = &sin_[(ty+ky)*36 + tx];
            const float* wrow = &s_w1[ky*5*24];
            #pragma unroll
            for (int kx = 0; kx < 5; ++kx) {
                float2 v = irow[kx];
                const float* wp = wrow + kx*24;
                #pragma unroll
                for (int c = 0; c < 12; ++c) {
                    ar[c] += v.x*wp[c]    - v.y*wp[12+c];
                    ai[c] += v.x*wp[12+c] + v.y*wp[c];
                }
            }
        }
        // relu + fp16 pack -> own-pixel slot (no barrier needed)
        int sl = tf % 3;
        #pragma unroll
        for (int c = 0; c < 12; ++c)
            s_h1[sl][c][tid] = __floats2half2_rn(fmaxf(ar[c],0.f), fmaxf(ai[c],0.f));

        // ---- output frame tc = tf-1 (slots tf-2..tf all available)
        if (tf >= 1) do_out(tf - 1);

        // ---- commit prefetched frame, single barrier per iteration
        if (pf) {
            s_in[(tf+1) & 1][tid] = p0;
            if (has1) s_in[(tf+1) & 1][i1_] = p1;
        }
        __syncthreads();
    }
    // final output frame
    do_out(NT - 1);
}

// ---------------- K2: Gram matrices G_b = M_b M_b^H  (80 x 5x5 complex Hermitian)
__global__ __launch_bounds__(256) void k_gram(
    const float* __restrict__ re, const float* __restrict__ im,
    float* __restrict__ gG)
{
    const int b = blockIdx.x;            // 0..79  = chunk*16 + i*4 + j
    const int chunk = b >> 4;
    const int pidx = b & 15;
    const int X0 = (pidx >> 2) * SXY;
    const int Y0 = (pidx & 3) * SXY;
    const int tid = threadIdx.x;

    float acc[50];
    #pragma unroll
    for (int k = 0; k < 50; ++k) acc[k] = 0.f;

    const int npx = PXY * PXY;           // 13225
    for (int pi = tid; pi < npx; pi += 256) {
        int px = pi / PXY, py = pi % PXY;
        size_t base = (size_t)(X0 + px) * NXY + (Y0 + py);
        float xr[5], xi[5];
        #pragma unroll
        for (int r = 0; r < 5; ++r) {
            size_t a = (size_t)(chunk*5 + r) * NPIX + base;
            xr[r] = re[a]; xi[r] = im[a];
        }
        #pragma unroll
        for (int t1 = 0; t1 < 5; ++t1)
            #pragma unroll
            for (int t2 = 0; t2 < 5; ++t2) {
                acc[(t1*5+t2)*2]   += xr[t1]*xr[t2] + xi[t1]*xi[t2];
                acc[(t1*5+t2)*2+1] += xi[t1]*xr[t2] - xr[t1]*xi[t2];
            }
    }
    #pragma unroll
    for (int k = 0; k < 50; ++k) {
        float v = acc[k];
        for (int m = 32; m > 0; m >>= 1) v += __shfl_xor(v, m, 64);
        acc[k] = v;
    }
    __shared__ float s_red[4][50];
    int lane = tid & 63, wid = tid >> 6;
    if (lane == 0) {
        #pragma unroll
        for (int k = 0; k < 50; ++k) s_red[wid][k] = acc[k];
    }
    __syncthreads();
    if (tid < 50) {
        gG[b*50 + tid] = s_red[0][tid] + s_red[1][tid] + s_red[2][tid] + s_red[3][tid];
    }
}

// ---------------- K3: 5x5 complex Hermitian Jacobi eigensolve -> W = V f(Lambda) V^H
__global__ void k_eig(const float* __restrict__ gG, const float* __restrict__ thres,
                      float* __restrict__ gW)
{
    int b = blockIdx.x * 64 + threadIdx.x;
    if (b >= 80) return;
    float Ar[5][5], Ai[5][5], Vr[5][5], Vi[5][5];
    #pragma unroll
    for (int a = 0; a < 5; ++a)
        #pragma unroll
        for (int c = 0; c < 5; ++c) {
            Ar[a][c] = gG[b*50 + (a*5+c)*2];
            Ai[a][c] = gG[b*50 + (a*5+c)*2 + 1];
            Vr[a][c] = (a==c) ? 1.f : 0.f;
            Vi[a][c] = 0.f;
        }
    for (int sw = 0; sw < 9; ++sw) {
        #pragma unroll
        for (int p = 0; p < 4; ++p) {
            #pragma unroll
            for (int q = p+1; q < 5; ++q) {
                float apr = Ar[p][q], api = Ai[p][q];
                float n2 = apr*apr + api*api;
                if (n2 > 1e-24f) {
                    float mlen = sqrtf(n2);
                    float phr = apr / mlen, phi = api / mlen;
                    float tau = (Ar[q][q] - Ar[p][p]) / (2.f * mlen);
                    float tt = (tau >= 0.f ? 1.f : -1.f) / (fabsf(tau) + sqrtf(1.f + tau*tau));
                    float cc = 1.f / sqrtf(1.f + tt*tt);
                    float ss = tt * cc;
                    float wr2 = ss * phr, wi2 = ss * phi;   // w = s*e^{i phi}
                    #pragma unroll
                    for (int k = 0; k < 5; ++k) {
                        float xr = Ar[k][p], xi2 = Ai[k][p];
                        float yr = Ar[k][q], yi = Ai[k][q];
                        Ar[k][p] = cc*xr - (wr2*yr + wi2*yi);
                        Ai[k][p] = cc*xi2 - (wr2*yi - wi2*yr);
                        Ar[k][q] = wr2*xr - wi2*xi2 + cc*yr;
                        Ai[k][q] = wr2*xi2 + wi2*xr + cc*yi;
                        float vxr = Vr[k][p], vxi = Vi[k][p];
                        float vyr = Vr[k][q], vyi = Vi[k][q];
                        Vr[k][p] = cc*vxr - (wr2*vyr + wi2*vyi);
                        Vi[k][p] = cc*vxi - (wr2*vyi - wi2*vyr);
                        Vr[k][q] = wr2*vxr - wi2*vxi + cc*vyr;
                        Vi[k][q] = wr2*vxi + wi2*vxr + cc*vyi;
                    }
                    #pragma unroll
                    for (int k = 0; k < 5; ++k) {
                        float xr = Ar[p][k], xi2 = Ai[p][k];
                        float yr = Ar[q][k], yi = Ai[q][k];
                        Ar[p][k] = cc*xr - (wr2*yr - wi2*yi);
                        Ai[p][k] = cc*xi2 - (wr2*yi + wi2*yr);
                        Ar[q][k] = wr2*xr + wi2*xi2 + cc*yr;
                        Ai[q][k] = wr2*xi2 - wi2*xr + cc*yi;
                    }
                }
            }
        }
    }
    float sv[5], s0 = 0.f;
    #pragma unroll
    for (int k = 0; k < 5; ++k) { sv[k] = sqrtf(fmaxf(Ar[k][k], 0.f)); s0 = fmaxf(s0, sv[k]); }
    float th = fmaxf(thres[b], 0.f) * s0;
    float ratio[5];
    #pragma unroll
    for (int k = 0; k < 5; ++k)
        ratio[k] = sv[k] > 0.f ? fmaxf(sv[k] - th, 0.f) / sv[k] : 0.f;
    #pragma unroll
    for (int a = 0; a < 5; ++a)
        #pragma unroll
        for (int c = 0; c < 5; ++c) {
            float wr = 0.f, wi = 0.f;
            #pragma unroll
            for (int k = 0; k < 5; ++k) {
                wr += ratio[k] * (Vr[a][k]*Vr[c][k] + Vi[a][k]*Vi[c][k]);
                wi += ratio[k] * (Vi[a][k]*Vr[c][k] - Vr[a][k]*Vi[c][k]);
            }
            gW[b*50 + (a*5+c)*2]   = wr;
            gW[b*50 + (a*5+c)*2+1] = wi;
        }
}

// ---------------- K3b: region-averaged W (7x7 overlap regions per chunk), includes 1/cnt
__global__ void k_wavg(const float* __restrict__ gW, float* __restrict__ gA)
{
    int blk = blockIdx.x;         // chunk*49 + rx*7 + ry
    int e = threadIdx.x;
    if (e >= 25) return;
    int chunk = blk / 49;
    int rem = blk % 49;
    int rx = rem / 7, ry = rem % 7;
    int i0 = rx >> 1, i1 = (rx + 1) >> 1;
    int j0 = ry >> 1, j1 = (ry + 1) >> 1;
    float sr = 0.f, si = 0.f; int cnt = 0;
    for (int i = i0; i <= i1; ++i)
        for (int j = j0; j <= j1; ++j) {
            int b = chunk*16 + i*4 + j;
            sr += gW[b*50 + e*2];
            si += gW[b*50 + e*2 + 1];
            ++cnt;
        }
    float inv = 1.f / (float)cnt;
    gA[blk*50 + e*2]   = sr * inv;
    gA[blk*50 + e*2+1] = si * inv;
}

// ---------------- K4: q_re = Re(Wavg * x5) ; out += q_re*(1-p_w)   (fp32 RMW)
__global__ __launch_bounds__(256) void k_final(
    const float* __restrict__ re, const float* __restrict__ im,
    const float* __restrict__ gA, const float* __restrict__ p_w,
    float* __restrict__ out)
{
    int pix = blockIdx.x * 256 + threadIdx.x;
    int chunk = blockIdx.y;
    int X = pix / NXY, Y = pix % NXY;
    int i_lo = (X - 4) / SXY; if (i_lo < 0) i_lo = 0;
    int i_hi = X / SXY;       if (i_hi > 3) i_hi = 3;
    int j_lo = (Y - 4) / SXY; if (j_lo < 0) j_lo = 0;
    int j_hi = Y / SXY;       if (j_hi > 3) j_hi = 3;
    int rx = i_lo + i_hi, ry = j_lo + j_hi;
    const float* wa = gA + (size_t)(chunk*49 + rx*7 + ry) * 50;
    float Wr[5][5], Wi[5][5];
    #pragma unroll
    for (int a = 0; a < 5; ++a)
        #pragma unroll
        for (int r = 0; r < 5; ++r) {
            Wr[a][r] = wa[(a*5+r)*2];
            Wi[a][r] = wa[(a*5+r)*2+1];
        }
    float xr[5], xi[5];
    #pragma unroll
    for (int r = 0; r < 5; ++r) {
        size_t a = (size_t)(chunk*5+r)*NPIX + pix;
        xr[r] = re[a]; xi[r] = im[a];
    }
    float qwv = 1.f - p_w[0];
    #pragma unroll
    for (int tl = 0; tl < 5; ++tl) {
        float qr = 0.f;
        #pragma unroll
        for (int r = 0; r < 5; ++r)
            qr += Wr[tl][r]*xr[r] - Wi[tl][r]*xi[r];
        size_t idx = (size_t)(chunk*5+tl)*NPIX + pix;
        out[idx] += qr*qwv;
    }
}

extern "C" void kernel_launch(void* const* d_in, const int* in_sizes, int n_in,
                              void* d_out, int out_size, void* d_ws, size_t ws_size,
                              hipStream_t stream)
{
    const float* re    = (const float*)d_in[0];
    const float* im    = (const float*)d_in[1];
    const float* w1r   = (const float*)d_in[2];
    const float* w1i   = (const float*)d_in[3];
    const float* b1r   = (const float*)d_in[4];
    const float* b1i   = (const float*)d_in[5];
    const float* w2r   = (const float*)d_in[6];
    const float* w2i   = (const float*)d_in[7];
    const float* b2r   = (const float*)d_in[8];
    const float* b2i   = (const float*)d_in[9];
    const float* w3r   = (const float*)d_in[10];
    const float* w3i   = (const float*)d_in[11];
    const float* b3r   = (const float*)d_in[12];
    const float* thres = (const float*)d_in[14];
    const float* tau_w = (const float*)d_in[15];
    const float* p_w   = (const float*)d_in[16];
    const int* num_iter= (const int*)d_in[17];

    float* ws = (float*)d_ws;
    float* gG = ws;                 // 80*50 floats
    float* gW = gG + 80*50;         // 80*50 floats
    float* gA = gW + 80*50;         // 245*50 floats  (total ~81 KB)

    float* outf = (float*)d_out;

    dim3 g1(NXY/TW, NXY/TH);
    k_conv<<<g1, 256, 0, stream>>>(re, im, w1r, w1i, b1r, b1i, w2r, w2i,
                                   b2r, b2i, w3r, w3i, b3r,
                                   tau_w, p_w, num_iter, outf);
    k_gram<<<80, 256, 0, stream>>>(re, im, gG);
    k_eig<<<2, 64, 0, stream>>>(gG, thres, gW);
    k_wavg<<<245, 32, 0, stream>>>(gW, gA);
    dim3 g4(NPIX/256, 5);
    k_final<<<g4, 256, 0, stream>>>(re, im, gA, p_w, outf);
}

// Round 9
// 882.169 us; speedup vs baseline: 2.8454x; 1.6159x over previous
//
#include <hip/hip_runtime.h>
#include <hip/hip_fp16.h>

#define NT 25
#define NXY 448
#define NPIX (448*448)
#define PXY 115
#define SXY 111

#define TW 32
#define TH 8

typedef float vf2 __attribute__((ext_vector_type(2)));

// complex MAC via packed fp32: z += x * w  (z,x,w are (re,im) pairs)
//  pk1: z.lo += x.lo*w.lo ; z.hi += x.lo*w.hi      (xr*wr, xr*wi)
//  pk2: z.lo += -x.hi*w.hi ; z.hi += x.hi*w.lo     (-xi*wi, xi*wr)
#define CMAC(z, x, w)                                                                              \
    asm("v_pk_fma_f32 %0, %1, %2, %0 op_sel:[0,0,0] op_sel_hi:[0,1,1]"                             \
        : "+v"(z) : "v"(x), "v"(w));                                                               \
    asm("v_pk_fma_f32 %0, %1, %2, %0 op_sel:[1,1,0] op_sel_hi:[1,0,1] neg_lo:[0,1,0]"              \
        : "+v"(z) : "v"(x), "v"(w));

// ---------------- K1: fused complex conv1(1->12,5x5)+ReLU -> conv2(12->12,3 temporal)+ReLU
// -> conv3(12->1) real part ; out = (x_re - denR*tsc)*pwv   (fp32, [25,448,448])
__global__ __launch_bounds__(256) void k_conv(
    const float* __restrict__ re, const float* __restrict__ im,
    const float* __restrict__ w1r, const float* __restrict__ w1i,
    const float* __restrict__ b1r, const float* __restrict__ b1i,
    const float* __restrict__ w2r, const float* __restrict__ w2i,
    const float* __restrict__ b2r, const float* __restrict__ b2i,
    const float* __restrict__ w3r, const float* __restrict__ w3i,
    const float* __restrict__ b3r,
    const float* __restrict__ tau_w, const float* __restrict__ p_w,
    const int* __restrict__ num_iter,
    float* __restrict__ out)
{
    __shared__ vf2 s_w1v[25*12];          // [tap*12 + c] = (w1r, w1i)
    __shared__ vf2 s_w2v[36*12];          // [(c1*3+dt)*12 + c2] = (w2r, w2i)
    __shared__ vf2 s_b1v[12], s_b2v[12];
    __shared__ float s_w3r[12], s_w3i[12], s_b3[1];
    __shared__ vf2 s_inv[2][12*36];       // double-buffered input tile (re,im), 2-halo
    __shared__ __half2 s_h1[3][12][TH*TW];// per-pixel h1, 3 time slots (own-thread access)

    const int tid = threadIdx.x;
    const int tx = tid & 31;
    const int ty = tid >> 5;
    const int Y0 = blockIdx.x * TW;
    const int X0 = blockIdx.y * TH;

    for (int i = tid; i < 300; i += 256) {
        int c = i / 25, tap = i - c*25;                 // w1 global idx = c*25 + tap
        s_w1v[tap*12 + c] = (vf2){w1r[i], w1i[i]};
    }
    for (int i = tid; i < 432; i += 256) {
        int dt = i % 3; int t = i / 3; int c1 = t % 12; int c2 = t / 12; // i=(c2*12+c1)*3+dt
        s_w2v[(c1*3+dt)*12 + c2] = (vf2){w2r[i], w2i[i]};
    }
    if (tid < 12) {
        s_b1v[tid] = (vf2){b1r[tid], b1i[tid]};
        s_b2v[tid] = (vf2){b2r[tid], b2i[tid]};
        s_w3r[tid] = w3r[tid]; s_w3i[tid] = w3i[tid];
    }
    if (tid == 0) s_b3[0] = b3r[0];

    const float tsc = fmaxf(tau_w[0], 0.f) / (float)num_iter[0];
    const float pwv = fmaxf(p_w[0], 0.f);

    // conv2(+ReLU)+conv3+epilogue for output frame tc (reads own-pixel h1 slots)
    auto do_out = [&](int tc) {
        vf2 z[12];
        #pragma unroll
        for (int c = 0; c < 12; ++c) z[c] = s_b2v[c];
        #pragma unroll
        for (int dt = 0; dt < 3; ++dt) {
            int tt = tc - 1 + dt;
            if (tt >= 0 && tt < NT) {                  // wave-uniform branch
                int sl = tt % 3;
                #pragma unroll 1
                for (int c1 = 0; c1 < 12; ++c1) {
                    __half2 h = s_h1[sl][c1][tid];
                    vf2 x = (vf2){__low2float(h), __high2float(h)};
                    const vf2* wp = &s_w2v[(c1*3+dt)*12];
                    #pragma unroll
                    for (int c2 = 0; c2 < 12; ++c2) { CMAC(z[c2], x, wp[c2]); }
                }
            }
        }
        float dR = s_b3[0];
        #pragma unroll
        for (int c = 0; c < 12; ++c)
            dR += fmaxf(z[c].x,0.f)*s_w3r[c] - fmaxf(z[c].y,0.f)*s_w3i[c];
        size_t idx = (size_t)tc*NPIX + (size_t)(X0+ty)*NXY + (Y0+tx);
        out[idx] = (re[idx] - dR * tsc) * pwv;
    };

    #pragma unroll 1
    for (int tf = 0; tf < NT; ++tf) {
        // stage frame tf into buffer tf&1 (other buffer than the one being read)
        {
            const float* rp = re + (size_t)tf * NPIX;
            const float* ip = im + (size_t)tf * NPIX;
            vf2* dst = s_inv[tf & 1];
            for (int idx = tid; idx < 12*36; idx += 256) {
                int r = idx / 36, c = idx - r*36;
                int gx = X0 + r - 2, gy = Y0 + c - 2;
                bool ok = (gx >= 0) && (gx < NXY) && (gy >= 0) && (gy < NXY);
                int cgx = ok ? gx : 0, cgy = ok ? gy : 0;
                size_t a = (size_t)cgx * NXY + cgy;
                float vr = rp[a], vi = ip[a];
                dst[idx] = (vf2){ok ? vr : 0.f, ok ? vi : 0.f};
            }
        }
        __syncthreads();

        // ---- conv1: 12 complex accumulators, packed-fp32 MACs
        vf2 a[12];
        #pragma unroll
        for (int c = 0; c < 12; ++c) a[c] = s_b1v[c];
        const vf2* sin_ = s_inv[tf & 1];
        #pragma unroll 1
        for (int ky = 0; ky < 5; ++ky) {
            const vf2* irow = &sin_[(ty+ky)*36 + tx];
            const vf2* wrow = &s_w1v[ky*5*12];
            #pragma unroll
            for (int kx = 0; kx < 5; ++kx) {
                vf2 x = irow[kx];
                const vf2* wp = wrow + kx*12;
                #pragma unroll
                for (int c = 0; c < 12; ++c) { CMAC(a[c], x, wp[c]); }
            }
        }
        int sl = tf % 3;
        #pragma unroll
        for (int c = 0; c < 12; ++c)
            s_h1[sl][c][tid] = __floats2half2_rn(fmaxf(a[c].x,0.f), fmaxf(a[c].y,0.f));

        // ---- output frame tc = tf-1 (h1 slots tf-2..tf all valid, own-pixel: no barrier)
        if (tf >= 1) do_out(tf - 1);
    }
    do_out(NT - 1);
}

// ---------------- K2: Gram matrices G_b = M_b M_b^H  (80 x 5x5 complex Hermitian)
__global__ __launch_bounds__(256) void k_gram(
    const float* __restrict__ re, const float* __restrict__ im,
    float* __restrict__ gG)
{
    const int b = blockIdx.x;            // 0..79  = chunk*16 + i*4 + j
    const int chunk = b >> 4;
    const int pidx = b & 15;
    const int X0 = (pidx >> 2) * SXY;
    const int Y0 = (pidx & 3) * SXY;
    const int tid = threadIdx.x;

    float acc[50];
    #pragma unroll
    for (int k = 0; k < 50; ++k) acc[k] = 0.f;

    const int npx = PXY * PXY;           // 13225
    for (int pi = tid; pi < npx; pi += 256) {
        int px = pi / PXY, py = pi % PXY;
        size_t base = (size_t)(X0 + px) * NXY + (Y0 + py);
        float xr[5], xi[5];
        #pragma unroll
        for (int r = 0; r < 5; ++r) {
            size_t a = (size_t)(chunk*5 + r) * NPIX + base;
            xr[r] = re[a]; xi[r] = im[a];
        }
        #pragma unroll
        for (int t1 = 0; t1 < 5; ++t1)
            #pragma unroll
            for (int t2 = 0; t2 < 5; ++t2) {
                acc[(t1*5+t2)*2]   += xr[t1]*xr[t2] + xi[t1]*xi[t2];
                acc[(t1*5+t2)*2+1] += xi[t1]*xr[t2] - xr[t1]*xi[t2];
            }
    }
    #pragma unroll
    for (int k = 0; k < 50; ++k) {
        float v = acc[k];
        for (int m = 32; m > 0; m >>= 1) v += __shfl_xor(v, m, 64);
        acc[k] = v;
    }
    __shared__ float s_red[4][50];
    int lane = tid & 63, wid = tid >> 6;
    if (lane == 0) {
        #pragma unroll
        for (int k = 0; k < 50; ++k) s_red[wid][k] = acc[k];
    }
    __syncthreads();
    if (tid < 50) {
        gG[b*50 + tid] = s_red[0][tid] + s_red[1][tid] + s_red[2][tid] + s_red[3][tid];
    }
}

// ---------------- K3: 5x5 complex Hermitian Jacobi eigensolve -> W = V f(Lambda) V^H
__global__ void k_eig(const float* __restrict__ gG, const float* __restrict__ thres,
                      float* __restrict__ gW)
{
    int b = blockIdx.x * 64 + threadIdx.x;
    if (b >= 80) return;
    float Ar[5][5], Ai[5][5], Vr[5][5], Vi[5][5];
    #pragma unroll
    for (int a = 0; a < 5; ++a)
        #pragma unroll
        for (int c = 0; c < 5; ++c) {
            Ar[a][c] = gG[b*50 + (a*5+c)*2];
            Ai[a][c] = gG[b*50 + (a*5+c)*2 + 1];
            Vr[a][c] = (a==c) ? 1.f : 0.f;
            Vi[a][c] = 0.f;
        }
    for (int sw = 0; sw < 9; ++sw) {
        #pragma unroll
        for (int p = 0; p < 4; ++p) {
            #pragma unroll
            for (int q = p+1; q < 5; ++q) {
                float apr = Ar[p][q], api = Ai[p][q];
                float n2 = apr*apr + api*api;
                if (n2 > 1e-24f) {
                    float mlen = sqrtf(n2);
                    float phr = apr / mlen, phi = api / mlen;
                    float tau = (Ar[q][q] - Ar[p][p]) / (2.f * mlen);
                    float tt = (tau >= 0.f ? 1.f : -1.f) / (fabsf(tau) + sqrtf(1.f + tau*tau));
                    float cc = 1.f / sqrtf(1.f + tt*tt);
                    float ss = tt * cc;
                    float wr2 = ss * phr, wi2 = ss * phi;   // w = s*e^{i phi}
                    #pragma unroll
                    for (int k = 0; k < 5; ++k) {
                        float xr = Ar[k][p], xi2 = Ai[k][p];
                        float yr = Ar[k][q], yi = Ai[k][q];
                        Ar[k][p] = cc*xr - (wr2*yr + wi2*yi);
                        Ai[k][p] = cc*xi2 - (wr2*yi - wi2*yr);
                        Ar[k][q] = wr2*xr - wi2*xi2 + cc*yr;
                        Ai[k][q] = wr2*xi2 + wi2*xr + cc*yi;
                        float vxr = Vr[k][p], vxi = Vi[k][p];
                        float vyr = Vr[k][q], vyi = Vi[k][q];
                        Vr[k][p] = cc*vxr - (wr2*vyr + wi2*vyi);
                        Vi[k][p] = cc*vxi - (wr2*vyi - wi2*vyr);
                        Vr[k][q] = wr2*vxr - wi2*vxi + cc*vyr;
                        Vi[k][q] = wr2*vxi + wi2*vxr + cc*vyi;
                    }
                    #pragma unroll
                    for (int k = 0; k < 5; ++k) {
                        float xr = Ar[p][k], xi2 = Ai[p][k];
                        float yr = Ar[q][k], yi = Ai[q][k];
                        Ar[p][k] = cc*xr - (wr2*yr - wi2*yi);
                        Ai[p][k] = cc*xi2 - (wr2*yi + wi2*yr);
                        Ar[q][k] = wr2*xr + wi2*xi2 + cc*yr;
                        Ai[q][k] = wr2*xi2 - wi2*xr + cc*yi;
                    }
                }
            }
        }
    }
    float sv[5], s0 = 0.f;
    #pragma unroll
    for (int k = 0; k < 5; ++k) { sv[k] = sqrtf(fmaxf(Ar[k][k], 0.f)); s0 = fmaxf(s0, sv[k]); }
    float th = fmaxf(thres[b], 0.f) * s0;
    float ratio[5];
    #pragma unroll
    for (int k = 0; k < 5; ++k)
        ratio[k] = sv[k] > 0.f ? fmaxf(sv[k] - th, 0.f) / sv[k] : 0.f;
    #pragma unroll
    for (int a = 0; a < 5; ++a)
        #pragma unroll
        for (int c = 0; c < 5; ++c) {
            float wr = 0.f, wi = 0.f;
            #pragma unroll
            for (int k = 0; k < 5; ++k) {
                wr += ratio[k] * (Vr[a][k]*Vr[c][k] + Vi[a][k]*Vi[c][k]);
                wi += ratio[k] * (Vi[a][k]*Vr[c][k] - Vr[a][k]*Vi[c][k]);
            }
            gW[b*50 + (a*5+c)*2]   = wr;
            gW[b*50 + (a*5+c)*2+1] = wi;
        }
}

// ---------------- K3b: region-averaged W (7x7 overlap regions per chunk), includes 1/cnt
__global__ void k_wavg(const float* __restrict__ gW, float* __restrict__ gA)
{
    int blk = blockIdx.x;         // chunk*49 + rx*7 + ry
    int e = threadIdx.x;
    if (e >= 25) return;
    int chunk = blk / 49;
    int rem = blk % 49;
    int rx = rem / 7, ry = rem % 7;
    int i0 = rx >> 1, i1 = (rx + 1) >> 1;
    int j0 = ry >> 1, j1 = (ry + 1) >> 1;
    float sr = 0.f, si = 0.f; int cnt = 0;
    for (int i = i0; i <= i1; ++i)
        for (int j = j0; j <= j1; ++j) {
            int b = chunk*16 + i*4 + j;
            sr += gW[b*50 + e*2];
            si += gW[b*50 + e*2 + 1];
            ++cnt;
        }
    float inv = 1.f / (float)cnt;
    gA[blk*50 + e*2]   = sr * inv;
    gA[blk*50 + e*2+1] = si * inv;
}

// ---------------- K4: q_re = Re(Wavg * x5) ; out += q_re*(1-p_w)   (fp32 RMW)
__global__ __launch_bounds__(256) void k_final(
    const float* __restrict__ re, const float* __restrict__ im,
    const float* __restrict__ gA, const float* __restrict__ p_w,
    float* __restrict__ out)
{
    int pix = blockIdx.x * 256 + threadIdx.x;
    int chunk = blockIdx.y;
    int X = pix / NXY, Y = pix % NXY;
    int i_lo = (X - 4) / SXY; if (i_lo < 0) i_lo = 0;
    int i_hi = X / SXY;       if (i_hi > 3) i_hi = 3;
    int j_lo = (Y - 4) / SXY; if (j_lo < 0) j_lo = 0;
    int j_hi = Y / SXY;       if (j_hi > 3) j_hi = 3;
    int rx = i_lo + i_hi, ry = j_lo + j_hi;
    const float* wa = gA + (size_t)(chunk*49 + rx*7 + ry) * 50;
    float Wr[5][5], Wi[5][5];
    #pragma unroll
    for (int a = 0; a < 5; ++a)
        #pragma unroll
        for (int r = 0; r < 5; ++r) {
            Wr[a][r] = wa[(a*5+r)*2];
            Wi[a][r] = wa[(a*5+r)*2+1];
        }
    float xr[5], xi[5];
    #pragma unroll
    for (int r = 0; r < 5; ++r) {
        size_t a = (size_t)(chunk*5+r)*NPIX + pix;
        xr[r] = re[a]; xi[r] = im[a];
    }
    float qwv = 1.f - p_w[0];
    #pragma unroll
    for (int tl = 0; tl < 5; ++tl) {
        float qr = 0.f;
        #pragma unroll
        for (int r = 0; r < 5; ++r)
            qr += Wr[tl][r]*xr[r] - Wi[tl][r]*xi[r];
        size_t idx = (size_t)(chunk*5+tl)*NPIX + pix;
        out[idx] += qr*qwv;
    }
}

extern "C" void kernel_launch(void* const* d_in, const int* in_sizes, int n_in,
                              void* d_out, int out_size, void* d_ws, size_t ws_size,
                              hipStream_t stream)
{
    const float* re    = (const float*)d_in[0];
    const float* im    = (const float*)d_in[1];
    const float* w1r   = (const float*)d_in[2];
    const float* w1i   = (const float*)d_in[3];
    const float* b1r   = (const float*)d_in[4];
    const float* b1i   = (const float*)d_in[5];
    const float* w2r   = (const float*)d_in[6];
    const float* w2i   = (const float*)d_in[7];
    const float* b2r   = (const float*)d_in[8];
    const float* b2i   = (const float*)d_in[9];
    const float* w3r   = (const float*)d_in[10];
    const float* w3i   = (const float*)d_in[11];
    const float* b3r   = (const float*)d_in[12];
    const float* thres = (const float*)d_in[14];
    const float* tau_w = (const float*)d_in[15];
    const float* p_w   = (const float*)d_in[16];
    const int* num_iter= (const int*)d_in[17];

    float* ws = (float*)d_ws;
    float* gG = ws;                 // 80*50 floats
    float* gW = gG + 80*50;         // 80*50 floats
    float* gA = gW + 80*50;         // 245*50 floats  (total ~81 KB)

    float* outf = (float*)d_out;

    dim3 g1(NXY/TW, NXY/TH);
    k_conv<<<g1, 256, 0, stream>>>(re, im, w1r, w1i, b1r, b1i, w2r, w2i,
                                   b2r, b2i, w3r, w3i, b3r,
                                   tau_w, p_w, num_iter, outf);
    k_gram<<<80, 256, 0, stream>>>(re, im, gG);
    k_eig<<<2, 64, 0, stream>>>(gG, thres, gW);
    k_wavg<<<245, 32, 0, stream>>>(gW, gA);
    dim3 g4(NPIX/256, 5);
    k_final<<<g4, 256, 0, stream>>>(re, im, gA, p_w, outf);
}

// Round 10
// 764.171 us; speedup vs baseline: 3.2848x; 1.1544x over previous
//
#include <hip/hip_runtime.h>
#include <hip/hip_fp16.h>

#define NT 25
#define NXY 448
#define NPIX (448*448)
#define PXY 115
#define SXY 111

#define TW 32
#define TH 8

typedef float vf2 __attribute__((ext_vector_type(2)));

// complex MAC via packed fp32: z += x * w  (z,x,w are (re,im) pairs)
//  pk1: z.lo += x.lo*w.lo ; z.hi += x.lo*w.hi      (xr*wr, xr*wi)
//  pk2: z.lo += -x.hi*w.hi ; z.hi += x.hi*w.lo     (-xi*wi, xi*wr)
#define CMAC(z, x, w)                                                                              \
    asm("v_pk_fma_f32 %0, %1, %2, %0 op_sel:[0,0,0] op_sel_hi:[0,1,1]"                             \
        : "+v"(z) : "v"(x), "v"(w));                                                               \
    asm("v_pk_fma_f32 %0, %1, %2, %0 op_sel:[1,1,0] op_sel_hi:[1,0,1] neg_lo:[0,1,0]"              \
        : "+v"(z) : "v"(x), "v"(w));

// ---------------- K1: fused complex conv1(1->12,5x5)+ReLU -> conv2(12->12,3 temporal)+ReLU
// -> conv3(12->1) real part ; out = (x_re - denR*tsc)*pwv   (fp32, [25,448,448])
// h1 in persistent per-thread registers (3 rotating slots, fp16-packed); LDS only for
// weights + double-buffered input tile. 4 blocks/CU -> entire 784-block grid co-resident.
__global__ __launch_bounds__(256, 4) void k_conv(
    const float* __restrict__ re, const float* __restrict__ im,
    const float* __restrict__ w1r, const float* __restrict__ w1i,
    const float* __restrict__ b1r, const float* __restrict__ b1i,
    const float* __restrict__ w2r, const float* __restrict__ w2i,
    const float* __restrict__ b2r, const float* __restrict__ b2i,
    const float* __restrict__ w3r, const float* __restrict__ w3i,
    const float* __restrict__ b3r,
    const float* __restrict__ tau_w, const float* __restrict__ p_w,
    const int* __restrict__ num_iter,
    float* __restrict__ out)
{
    __shared__ vf2 s_w1v[25*12];          // [tap*12 + c] = (w1r, w1i)
    __shared__ vf2 s_w2v[36*12];          // [(c1*3+dt)*12 + c2] = (w2r, w2i)
    __shared__ vf2 s_b1v[12], s_b2v[12];
    __shared__ float s_w3r[12], s_w3i[12], s_b3[1];
    __shared__ vf2 s_inv[2][12*36];       // double-buffered input tile (re,im), 2-halo

    const int tid = threadIdx.x;
    const int tx = tid & 31;
    const int ty = tid >> 5;
    const int Y0 = blockIdx.x * TW;
    const int X0 = blockIdx.y * TH;

    for (int i = tid; i < 300; i += 256) {
        int c = i / 25, tap = i - c*25;                 // w1 global idx = c*25 + tap
        s_w1v[tap*12 + c] = (vf2){w1r[i], w1i[i]};
    }
    for (int i = tid; i < 432; i += 256) {
        int dt = i % 3; int t = i / 3; int c1 = t % 12; int c2 = t / 12; // i=(c2*12+c1)*3+dt
        s_w2v[(c1*3+dt)*12 + c2] = (vf2){w2r[i], w2i[i]};
    }
    if (tid < 12) {
        s_b1v[tid] = (vf2){b1r[tid], b1i[tid]};
        s_b2v[tid] = (vf2){b2r[tid], b2i[tid]};
        s_w3r[tid] = w3r[tid]; s_w3i[tid] = w3i[tid];
    }
    if (tid == 0) s_b3[0] = b3r[0];

    const float tsc = fmaxf(tau_w[0], 0.f) / (float)num_iter[0];
    const float pwv = fmaxf(p_w[0], 0.f);

    // persistent h1 slots: hA = frame tc-1, hB = frame tc, hC = frame tc+1 (relu'd, fp16 pairs)
    __half2 hA[12], hB[12], hC[12];
    #pragma unroll
    for (int c = 0; c < 12; ++c) { hA[c] = __half2{}; hB[c] = __half2{}; hC[c] = __half2{}; }

    // stage frame tf into buffer tf&1
    auto stage = [&](int tf) {
        const float* rp = re + (size_t)tf * NPIX;
        const float* ip = im + (size_t)tf * NPIX;
        vf2* dst = s_inv[tf & 1];
        for (int idx = tid; idx < 12*36; idx += 256) {
            int r = idx / 36, c = idx - r*36;
            int gx = X0 + r - 2, gy = Y0 + c - 2;
            bool ok = (gx >= 0) && (gx < NXY) && (gy >= 0) && (gy < NXY);
            int cgx = ok ? gx : 0, cgy = ok ? gy : 0;
            size_t a = (size_t)cgx * NXY + cgy;
            float vr = rp[a], vi = ip[a];
            dst[idx] = (vf2){ok ? vr : 0.f, ok ? vi : 0.f};
        }
    };

    // conv1 for frame tf -> relu -> fp16-pack into hs (register array, static indexing)
    auto conv1_to = [&](int tf, __half2 (&hs)[12]) {
        vf2 a[12];
        #pragma unroll
        for (int c = 0; c < 12; ++c) a[c] = s_b1v[c];
        const vf2* sin_ = s_inv[tf & 1];
        #pragma unroll 1
        for (int ky = 0; ky < 5; ++ky) {
            const vf2* irow = &sin_[(ty+ky)*36 + tx];
            const vf2* wrow = &s_w1v[ky*5*12];
            #pragma unroll
            for (int kx = 0; kx < 5; ++kx) {
                vf2 x = irow[kx];
                const vf2* wp = wrow + kx*12;
                #pragma unroll
                for (int c = 0; c < 12; ++c) { CMAC(a[c], x, wp[c]); }
            }
        }
        #pragma unroll
        for (int c = 0; c < 12; ++c)
            hs[c] = __floats2half2_rn(fmaxf(a[c].x,0.f), fmaxf(a[c].y,0.f));
    };

    // conv2(+ReLU)+conv3+epilogue for output frame tc; h slots passed by reference (static)
    auto do_out = [&](int tc, __half2 (&hp)[12], __half2 (&hc)[12], __half2 (&hn)[12],
                      bool hasP, bool hasN) {
        vf2 z[12];
        #pragma unroll
        for (int c = 0; c < 12; ++c) z[c] = s_b2v[c];
        if (hasP) {
            #pragma unroll
            for (int c1 = 0; c1 < 12; ++c1) {
                vf2 x = (vf2){__low2float(hp[c1]), __high2float(hp[c1])};
                const vf2* wp = &s_w2v[(c1*3+0)*12];
                #pragma unroll
                for (int c2 = 0; c2 < 12; ++c2) { CMAC(z[c2], x, wp[c2]); }
            }
        }
        {
            #pragma unroll
            for (int c1 = 0; c1 < 12; ++c1) {
                vf2 x = (vf2){__low2float(hc[c1]), __high2float(hc[c1])};
                const vf2* wp = &s_w2v[(c1*3+1)*12];
                #pragma unroll
                for (int c2 = 0; c2 < 12; ++c2) { CMAC(z[c2], x, wp[c2]); }
            }
        }
        if (hasN) {
            #pragma unroll
            for (int c1 = 0; c1 < 12; ++c1) {
                vf2 x = (vf2){__low2float(hn[c1]), __high2float(hn[c1])};
                const vf2* wp = &s_w2v[(c1*3+2)*12];
                #pragma unroll
                for (int c2 = 0; c2 < 12; ++c2) { CMAC(z[c2], x, wp[c2]); }
            }
        }
        float dR = s_b3[0];
        #pragma unroll
        for (int c = 0; c < 12; ++c)
            dR += fmaxf(z[c].x,0.f)*s_w3r[c] - fmaxf(z[c].y,0.f)*s_w3i[c];
        size_t idx = (size_t)tc*NPIX + (size_t)(X0+ty)*NXY + (Y0+tx);
        out[idx] = (re[idx] - dR * tsc) * pwv;
    };

    // frame 0
    stage(0);
    __syncthreads();
    conv1_to(0, hB);

    #pragma unroll 1
    for (int tf = 1; tf < NT; ++tf) {
        stage(tf);                 // writes buf tf&1; other waves read buf (tf-1)&1 only
        __syncthreads();
        conv1_to(tf, hC);
        do_out(tf - 1, hA, hB, hC, (tf - 1) >= 1, true);
        #pragma unroll
        for (int c = 0; c < 12; ++c) { hA[c] = hB[c]; hB[c] = hC[c]; }
    }
    // final frame tc = 24: hA=h[23], hB=h[24]
    do_out(NT - 1, hA, hB, hC, true, false);
}

// ---------------- K2: Gram matrices G_b = M_b M_b^H  (80 x 5x5 complex Hermitian)
__global__ __launch_bounds__(256) void k_gram(
    const float* __restrict__ re, const float* __restrict__ im,
    float* __restrict__ gG)
{
    const int b = blockIdx.x;            // 0..79  = chunk*16 + i*4 + j
    const int chunk = b >> 4;
    const int pidx = b & 15;
    const int X0 = (pidx >> 2) * SXY;
    const int Y0 = (pidx & 3) * SXY;
    const int tid = threadIdx.x;

    float acc[50];
    #pragma unroll
    for (int k = 0; k < 50; ++k) acc[k] = 0.f;

    const int npx = PXY * PXY;           // 13225
    for (int pi = tid; pi < npx; pi += 256) {
        int px = pi / PXY, py = pi % PXY;
        size_t base = (size_t)(X0 + px) * NXY + (Y0 + py);
        float xr[5], xi[5];
        #pragma unroll
        for (int r = 0; r < 5; ++r) {
            size_t a = (size_t)(chunk*5 + r) * NPIX + base;
            xr[r] = re[a]; xi[r] = im[a];
        }
        #pragma unroll
        for (int t1 = 0; t1 < 5; ++t1)
            #pragma unroll
            for (int t2 = 0; t2 < 5; ++t2) {
                acc[(t1*5+t2)*2]   += xr[t1]*xr[t2] + xi[t1]*xi[t2];
                acc[(t1*5+t2)*2+1] += xi[t1]*xr[t2] - xr[t1]*xi[t2];
            }
    }
    #pragma unroll
    for (int k = 0; k < 50; ++k) {
        float v = acc[k];
        for (int m = 32; m > 0; m >>= 1) v += __shfl_xor(v, m, 64);
        acc[k] = v;
    }
    __shared__ float s_red[4][50];
    int lane = tid & 63, wid = tid >> 6;
    if (lane == 0) {
        #pragma unroll
        for (int k = 0; k < 50; ++k) s_red[wid][k] = acc[k];
    }
    __syncthreads();
    if (tid < 50) {
        gG[b*50 + tid] = s_red[0][tid] + s_red[1][tid] + s_red[2][tid] + s_red[3][tid];
    }
}

// ---------------- K3: 5x5 complex Hermitian Jacobi eigensolve -> W = V f(Lambda) V^H
__global__ void k_eig(const float* __restrict__ gG, const float* __restrict__ thres,
                      float* __restrict__ gW)
{
    int b = blockIdx.x * 64 + threadIdx.x;
    if (b >= 80) return;
    float Ar[5][5], Ai[5][5], Vr[5][5], Vi[5][5];
    #pragma unroll
    for (int a = 0; a < 5; ++a)
        #pragma unroll
        for (int c = 0; c < 5; ++c) {
            Ar[a][c] = gG[b*50 + (a*5+c)*2];
            Ai[a][c] = gG[b*50 + (a*5+c)*2 + 1];
            Vr[a][c] = (a==c) ? 1.f : 0.f;
            Vi[a][c] = 0.f;
        }
    for (int sw = 0; sw < 9; ++sw) {
        #pragma unroll
        for (int p = 0; p < 4; ++p) {
            #pragma unroll
            for (int q = p+1; q < 5; ++q) {
                float apr = Ar[p][q], api = Ai[p][q];
                float n2 = apr*apr + api*api;
                if (n2 > 1e-24f) {
                    float mlen = sqrtf(n2);
                    float phr = apr / mlen, phi = api / mlen;
                    float tau = (Ar[q][q] - Ar[p][p]) / (2.f * mlen);
                    float tt = (tau >= 0.f ? 1.f : -1.f) / (fabsf(tau) + sqrtf(1.f + tau*tau));
                    float cc = 1.f / sqrtf(1.f + tt*tt);
                    float ss = tt * cc;
                    float wr2 = ss * phr, wi2 = ss * phi;   // w = s*e^{i phi}
                    #pragma unroll
                    for (int k = 0; k < 5; ++k) {
                        float xr = Ar[k][p], xi2 = Ai[k][p];
                        float yr = Ar[k][q], yi = Ai[k][q];
                        Ar[k][p] = cc*xr - (wr2*yr + wi2*yi);
                        Ai[k][p] = cc*xi2 - (wr2*yi - wi2*yr);
                        Ar[k][q] = wr2*xr - wi2*xi2 + cc*yr;
                        Ai[k][q] = wr2*xi2 + wi2*xr + cc*yi;
                        float vxr = Vr[k][p], vxi = Vi[k][p];
                        float vyr = Vr[k][q], vyi = Vi[k][q];
                        Vr[k][p] = cc*vxr - (wr2*vyr + wi2*vyi);
                        Vi[k][p] = cc*vxi - (wr2*vyi - wi2*vyr);
                        Vr[k][q] = wr2*vxr - wi2*vxi + cc*vyr;
                        Vi[k][q] = wr2*vxi + wi2*vxr + cc*vyi;
                    }
                    #pragma unroll
                    for (int k = 0; k < 5; ++k) {
                        float xr = Ar[p][k], xi2 = Ai[p][k];
                        float yr = Ar[q][k], yi = Ai[q][k];
                        Ar[p][k] = cc*xr - (wr2*yr - wi2*yi);
                        Ai[p][k] = cc*xi2 - (wr2*yi + wi2*yr);
                        Ar[q][k] = wr2*xr + wi2*xi2 + cc*yr;
                        Ai[q][k] = wr2*xi2 - wi2*xr + cc*yi;
                    }
                }
            }
        }
    }
    float sv[5], s0 = 0.f;
    #pragma unroll
    for (int k = 0; k < 5; ++k) { sv[k] = sqrtf(fmaxf(Ar[k][k], 0.f)); s0 = fmaxf(s0, sv[k]); }
    float th = fmaxf(thres[b], 0.f) * s0;
    float ratio[5];
    #pragma unroll
    for (int k = 0; k < 5; ++k)
        ratio[k] = sv[k] > 0.f ? fmaxf(sv[k] - th, 0.f) / sv[k] : 0.f;
    #pragma unroll
    for (int a = 0; a < 5; ++a)
        #pragma unroll
        for (int c = 0; c < 5; ++c) {
            float wr = 0.f, wi = 0.f;
            #pragma unroll
            for (int k = 0; k < 5; ++k) {
                wr += ratio[k] * (Vr[a][k]*Vr[c][k] + Vi[a][k]*Vi[c][k]);
                wi += ratio[k] * (Vi[a][k]*Vr[c][k] - Vr[a][k]*Vi[c][k]);
            }
            gW[b*50 + (a*5+c)*2]   = wr;
            gW[b*50 + (a*5+c)*2+1] = wi;
        }
}

// ---------------- K3b: region-averaged W (7x7 overlap regions per chunk), includes 1/cnt
__global__ void k_wavg(const float* __restrict__ gW, float* __restrict__ gA)
{
    int blk = blockIdx.x;         // chunk*49 + rx*7 + ry
    int e = threadIdx.x;
    if (e >= 25) return;
    int chunk = blk / 49;
    int rem = blk % 49;
    int rx = rem / 7, ry = rem % 7;
    int i0 = rx >> 1, i1 = (rx + 1) >> 1;
    int j0 = ry >> 1, j1 = (ry + 1) >> 1;
    float sr = 0.f, si = 0.f; int cnt = 0;
    for (int i = i0; i <= i1; ++i)
        for (int j = j0; j <= j1; ++j) {
            int b = chunk*16 + i*4 + j;
            sr += gW[b*50 + e*2];
            si += gW[b*50 + e*2 + 1];
            ++cnt;
        }
    float inv = 1.f / (float)cnt;
    gA[blk*50 + e*2]   = sr * inv;
    gA[blk*50 + e*2+1] = si * inv;
}

// ---------------- K4: q_re = Re(Wavg * x5) ; out += q_re*(1-p_w)   (fp32 RMW)
__global__ __launch_bounds__(256) void k_final(
    const float* __restrict__ re, const float* __restrict__ im,
    const float* __restrict__ gA, const float* __restrict__ p_w,
    float* __restrict__ out)
{
    int pix = blockIdx.x * 256 + threadIdx.x;
    int chunk = blockIdx.y;
    int X = pix / NXY, Y = pix % NXY;
    int i_lo = (X - 4) / SXY; if (i_lo < 0) i_lo = 0;
    int i_hi = X / SXY;       if (i_hi > 3) i_hi = 3;
    int j_lo = (Y - 4) / SXY; if (j_lo < 0) j_lo = 0;
    int j_hi = Y / SXY;       if (j_hi > 3) j_hi = 3;
    int rx = i_lo + i_hi, ry = j_lo + j_hi;
    const float* wa = gA + (size_t)(chunk*49 + rx*7 + ry) * 50;
    float Wr[5][5], Wi[5][5];
    #pragma unroll
    for (int a = 0; a < 5; ++a)
        #pragma unroll
        for (int r = 0; r < 5; ++r) {
            Wr[a][r] = wa[(a*5+r)*2];
            Wi[a][r] = wa[(a*5+r)*2+1];
        }
    float xr[5], xi[5];
    #pragma unroll
    for (int r = 0; r < 5; ++r) {
        size_t a = (size_t)(chunk*5+r)*NPIX + pix;
        xr[r] = re[a]; xi[r] = im[a];
    }
    float qwv = 1.f - p_w[0];
    #pragma unroll
    for (int tl = 0; tl < 5; ++tl) {
        float qr = 0.f;
        #pragma unroll
        for (int r = 0; r < 5; ++r)
            qr += Wr[tl][r]*xr[r] - Wi[tl][r]*xi[r];
        size_t idx = (size_t)(chunk*5+tl)*NPIX + pix;
        out[idx] += qr*qwv;
    }
}

extern "C" void kernel_launch(void* const* d_in, const int* in_sizes, int n_in,
                              void* d_out, int out_size, void* d_ws, size_t ws_size,
                              hipStream_t stream)
{
    const float* re    = (const float*)d_in[0];
    const float* im    = (const float*)d_in[1];
    const float* w1r   = (const float*)d_in[2];
    const float* w1i   = (const float*)d_in[3];
    const float* b1r   = (const float*)d_in[4];
    const float* b1i   = (const float*)d_in[5];
    const float* w2r   = (const float*)d_in[6];
    const float* w2i   = (const float*)d_in[7];
    const float* b2r   = (const float*)d_in[8];
    const float* b2i   = (const float*)d_in[9];
    const float* w3r   = (const float*)d_in[10];
    const float* w3i   = (const float*)d_in[11];
    const float* b3r   = (const float*)d_in[12];
    const float* thres = (const float*)d_in[14];
    const float* tau_w = (const float*)d_in[15];
    const float* p_w   = (const float*)d_in[16];
    const int* num_iter= (const int*)d_in[17];

    float* ws = (float*)d_ws;
    float* gG = ws;                 // 80*50 floats
    float* gW = gG + 80*50;         // 80*50 floats
    float* gA = gW + 80*50;         // 245*50 floats  (total ~81 KB)

    float* outf = (float*)d_out;

    dim3 g1(NXY/TW, NXY/TH);
    k_conv<<<g1, 256, 0, stream>>>(re, im, w1r, w1i, b1r, b1i, w2r, w2i,
                                   b2r, b2i, w3r, w3i, b3r,
                                   tau_w, p_w, num_iter, outf);
    k_gram<<<80, 256, 0, stream>>>(re, im, gG);
    k_eig<<<2, 64, 0, stream>>>(gG, thres, gW);
    k_wavg<<<245, 32, 0, stream>>>(gW, gA);
    dim3 g4(NPIX/256, 5);
    k_final<<<g4, 256, 0, stream>>>(re, im, gA, p_w, outf);
}